// Round 21
// baseline (184.071 us; speedup 1.0000x reference)
//
#include <hip/hip_runtime.h>

static constexpr int NN = 50000;   // nodes
static constexpr int NE = 800000;  // edges
static constexpr int NBUCK = (NN + 127) / 128;  // 391 buckets (dst >> 7)
static constexpr int CAP = 4096;   // staging capacity per bucket

typedef __attribute__((ext_vector_type(8))) short bf16x8;
typedef __attribute__((ext_vector_type(4))) float f32x4;

__device__ __forceinline__ float bf2f(ushort u) {
    union { unsigned int i; float f; } c; c.i = ((unsigned int)u) << 16; return c.f;
}
__device__ __forceinline__ ushort f2bf(float f) {
    union { float f; unsigned int i; } c; c.f = f;
    unsigned int x = c.i;
    return (ushort)((x + 0x7FFFu + ((x >> 16) & 1u)) >> 16);
}
__device__ __forceinline__ int packbf(float a, float b) {
    return (int)f2bf(a) | ((int)f2bf(b) << 16);
}
__device__ __forceinline__ void acc_add(float* acc, const int4 v) {
    acc[0] += bf2f((ushort)(v.x & 0xffff));
    acc[1] += bf2f((ushort)((unsigned)v.x >> 16));
    acc[2] += bf2f((ushort)(v.y & 0xffff));
    acc[3] += bf2f((ushort)((unsigned)v.y >> 16));
    acc[4] += bf2f((ushort)(v.z & 0xffff));
    acc[5] += bf2f((ushort)((unsigned)v.z >> 16));
    acc[6] += bf2f((ushort)(v.w & 0xffff));
    acc[7] += bf2f((ushort)((unsigned)v.w >> 16));
}
__device__ __forceinline__ void acc_mad(float* acc, const int4 v, const float s) {
    acc[0] += bf2f((ushort)(v.x & 0xffff)) * s;
    acc[1] += bf2f((ushort)((unsigned)v.x >> 16)) * s;
    acc[2] += bf2f((ushort)(v.y & 0xffff)) * s;
    acc[3] += bf2f((ushort)((unsigned)v.y >> 16)) * s;
    acc[4] += bf2f((ushort)(v.z & 0xffff)) * s;
    acc[5] += bf2f((ushort)((unsigned)v.z >> 16)) * s;
    acc[6] += bf2f((ushort)(v.w & 0xffff)) * s;
    acc[7] += bf2f((ushort)((unsigned)v.w >> 16)) * s;
}

// ---------------- prep: weight transposes + bcur zero ----------------
__global__ void transpose_all(const float* __restrict__ W1, const float* __restrict__ Wg1,
                              const float* __restrict__ Whv, const float* __restrict__ Wg2,
                              ushort* __restrict__ Wt1, ushort* __restrict__ Wtg1,
                              ushort* __restrict__ Whvt, ushort* __restrict__ Wg2t,
                              float* __restrict__ wval, int* __restrict__ bcur)
{
    int idx = blockIdx.x * blockDim.x + threadIdx.x;
    if (idx < 128 * 256) {                 // Wt1 [128][256] <- W1 [256][128]
        const int n = idx >> 8, k = idx & 255;
        Wt1[idx] = f2bf(W1[k * 128 + n]);
        return;
    }
    idx -= 128 * 256;
    if (idx < 256 * 160) {                 // Wtg1 [256][160] <- Wg1 [130][256]
        const int n = idx / 160, k = idx - n * 160;
        Wtg1[idx] = (k < 130) ? f2bf(Wg1[k * 256 + n]) : (ushort)0;
        return;
    }
    idx -= 256 * 160;
    if (idx < 256 * 256) {                 // Whvt [256][256] <- Whv [256][256]
        const int n = idx >> 8, k = idx & 255;
        Whvt[idx] = f2bf(Whv[k * 256 + n]);
        return;
    }
    idx -= 256 * 256;
    if (idx < 128 * 128) {                 // Wg2t [128][128] <- Wg2 [128][129] cols 0..127
        const int n = idx >> 7, k = idx & 127;
        Wg2t[idx] = f2bf(Wg2[k * 129 + n]);
        return;
    }
    idx -= 128 * 128;
    if (idx < 128) { wval[idx] = Wg2[idx * 129 + 128]; return; }
    idx -= 128;
    if (idx < NBUCK) bcur[idx] = 0;
}

// ---------------- COMBINED: gemm1 (blocks < gemmBlocks) + bucket_edges -----
__global__ __launch_bounds__(512) void gemm1_bucket(
    const float* __restrict__ x, const ushort* __restrict__ Wt1,
    const float* __restrict__ b1, ushort* __restrict__ h, int M, int gemmBlocks,
    const int* __restrict__ src, const int* __restrict__ dst,
    int* __restrict__ bcur, unsigned* __restrict__ staging, int e)
{
    __shared__ __align__(16) ushort pool[20480];   // 40 KB

    if (blockIdx.x >= gemmBlocks) {
        // ---------------- bucket_edges (512 threads) ----------------
        int* bins  = (int*)pool;
        int* gbase = bins + NBUCK;
        int* cur   = gbase + NBUCK;
        const int t = threadIdx.x;
        const int base = (blockIdx.x - gemmBlocks) * 2048;
        for (int i = t; i < NBUCK; i += 512) bins[i] = 0;
        __syncthreads();
        const int lim = min(2048, e - base);
        for (int i = t; i < lim; i += 512)
            atomicAdd(&bins[dst[base + i] >> 7], 1);
        __syncthreads();
        for (int i = t; i < NBUCK; i += 512) {
            cur[i] = 0;
            gbase[i] = bins[i] ? atomicAdd(&bcur[i], bins[i]) : 0;
        }
        __syncthreads();
        for (int i = t; i < lim; i += 512) {
            const int d = dst[base + i];
            const int b = d >> 7;
            const int r = atomicAdd(&cur[b], 1);
            staging[(size_t)b * CAP + gbase[b] + r] =
                ((unsigned)(d & 127) << 16) | (unsigned)src[base + i];
        }
        return;
    }

    // ---------------- gemm1: K=256, NB=128, A f32 cast-on-stage ----------------
    ushort* A_s = pool;             // [2][128*40] = 10240
    ushort* W_s = pool + 10240;     // [2][128*40]

    const int tid  = threadIdx.x;
    const int row0 = blockIdx.x * 128;
    const int lane = tid & 63;
    const int wid  = tid >> 6;
    const int wr = wid >> 2;
    const int wc = wid & 3;
    const int lr = lane & 15;
    const int kg = lane >> 4;

    const int sr = tid >> 2;
    const int sc = (tid & 3) * 8;
    const bool rok = (row0 + sr) < M;
    const float* Agf = x + (size_t)(row0 + sr) * 256 + sc;
    const ushort* Wg0 = Wt1 + (size_t)sr * 256 + sc;

    int4 sa = make_int4(0,0,0,0), sw0 = sa;
    auto load_A = [&](int kk) {
        if (rok) {
            const float* p = Agf + kk * 32;
            const float4 f0 = *(const float4*)(p + 0);
            const float4 f1 = *(const float4*)(p + 4);
            sa.x = packbf(f0.x, f0.y); sa.y = packbf(f0.z, f0.w);
            sa.z = packbf(f1.x, f1.y); sa.w = packbf(f1.z, f1.w);
        } else sa = make_int4(0, 0, 0, 0);
    };
    auto load_W = [&](int kk) { sw0 = *(const int4*)(Wg0 + kk * 32); };
    auto store_A = [&](int buf) { *(int4*)&A_s[buf * 5120 + sr * 40 + sc] = sa; };
    auto store_W = [&](int buf) { *(int4*)&W_s[buf * 5120 + sr * 40 + sc] = sw0; };

    load_A(0); load_W(0);
    store_A(0); store_W(0);

    f32x4 acc[4][2];
#pragma unroll
    for (int m = 0; m < 4; ++m) {
        acc[m][0] = (f32x4){0.f, 0.f, 0.f, 0.f};
        acc[m][1] = (f32x4){0.f, 0.f, 0.f, 0.f};
    }

    const int abase = (wr * 64 + lr) * 40 + kg * 8;

    for (int kk = 0; kk < 8; ++kk) {
        if (kk + 1 < 8) { load_A(kk + 1); load_W(kk + 1); }
        __syncthreads();
        const ushort* Ab = &A_s[(kk & 1) * 5120];
        const ushort* Wb = &W_s[(kk & 1) * 5120];
        bf16x8 a[4], b[2];
#pragma unroll
        for (int m = 0; m < 4; ++m) a[m] = *(const bf16x8*)&Ab[abase + m * 16 * 40];
        b[0] = *(const bf16x8*)&Wb[(wc * 32 + lr) * 40 + kg * 8];
        b[1] = *(const bf16x8*)&Wb[(wc * 32 + 16 + lr) * 40 + kg * 8];
#pragma unroll
        for (int m = 0; m < 4; ++m) {
            acc[m][0] = __builtin_amdgcn_mfma_f32_16x16x32_bf16(a[m], b[0], acc[m][0], 0, 0, 0);
            acc[m][1] = __builtin_amdgcn_mfma_f32_16x16x32_bf16(a[m], b[1], acc[m][1], 0, 0, 0);
        }
        if (kk + 1 < 8) { store_A((kk + 1) & 1); store_W((kk + 1) & 1); }
    }

#pragma unroll
    for (int m = 0; m < 4; ++m) {
#pragma unroll
        for (int n = 0; n < 2; ++n) {
            const int c = wc * 32 + n * 16 + lr;
            const float bb = b1[c];
            const int r0 = row0 + wr * 64 + m * 16 + kg * 4;
#pragma unroll
            for (int r = 0; r < 4; ++r) {
                const int R = r0 + r;
                if (R >= M) continue;
                h[(size_t)R * 128 + c] = f2bf(fmaxf(acc[m][n][r] + bb, 0.f));
            }
        }
    }
}

// per-bucket counting sort; computes its own bucket prefix (no separate scan);
// emits rowptr, dis, prescaled ra2, and coalesced esrc.
__global__ __launch_bounds__(128) void sort_bucket(
    const unsigned* __restrict__ staging, const int* __restrict__ bcur,
    int* __restrict__ rowptr, float* __restrict__ dis, float2* __restrict__ ra2,
    const float* __restrict__ rw1, const float* __restrict__ act,
    ushort* __restrict__ esrc, int n, int e)
{
    __shared__ int bins[128];
    __shared__ int sdata[128];
    __shared__ int baseSh;
    __shared__ ushort outb[CAP];
    const int b = blockIdx.x;
    const int t = threadIdx.x;

    // ---- own prefix: base = sum(bcur[0..b)) ----
    int part = 0;
    for (int i = t; i < b; i += 128) part += bcur[i];
    sdata[t] = part;
    bins[t] = 0;
    __syncthreads();
#pragma unroll
    for (int off = 64; off > 0; off >>= 1) {
        if (t < off) sdata[t] += sdata[t + off];
        __syncthreads();
    }
    if (t == 0) baseSh = sdata[0];
    __syncthreads();
    const int base = baseSh;

    // ---- histogram ----
    const int m = bcur[b];
    const unsigned* sp = staging + (size_t)b * CAP;
    for (int i = t; i < m; i += 128) atomicAdd(&bins[sp[i] >> 16], 1);
    __syncthreads();
    const int v = bins[t];
    sdata[t] = v;
    __syncthreads();
#pragma unroll
    for (int off = 1; off < 128; off <<= 1) {
        const int u = (t >= off) ? sdata[t - off] : 0;
        __syncthreads();
        sdata[t] += u;
        __syncthreads();
    }
    const int excl = sdata[t] - v;
    bins[t] = excl;   // cursor
    const int node = (b << 7) + t;
    if (node < n) {
        rowptr[node] = base + excl;
        const float d = rsqrtf(1.0f + (float)v);
        dis[node] = d;
        ra2[node] = make_float2(rw1[node] * d, act[node] * d);
    }
    if (b == 0 && t == 0) rowptr[n] = e;
    __syncthreads();
    for (int i = t; i < m; i += 128) {
        const unsigned p = sp[i];
        const int r = atomicAdd(&bins[p >> 16], 1);
        outb[r] = (ushort)(p & 0xffffu);
    }
    __syncthreads();
    for (int i = t; i < m; i += 128) esrc[base + i] = outb[i];
}

// ---------------- bf16 MFMA GEMM (gemm4 only) -------------------------------
// VH: fused value head — wc==0 waves dot A rows with wval during the K-loop.
template<int K, int NB, bool VH>
__global__ __launch_bounds__(512) void gemm_mfma(
    const void* __restrict__ Aptr, int lda, int M,
    const ushort* __restrict__ Wt,
    const float* __restrict__ bias,
    void* __restrict__ Cout, int ldc,
    const float* __restrict__ wval, const float* __restrict__ bg2full,
    float* __restrict__ vout)
{
    constexpr int NK = K / 32;
    constexpr int CF = NB / 64;
    __shared__ ushort A_s[2][128 * 40];
    __shared__ ushort W_s[2][NB * 40];

    const int tid  = threadIdx.x;
    const int row0 = blockIdx.x * 128;
    const int lane = tid & 63;
    const int wid  = tid >> 6;
    const int wr = wid >> 2;
    const int wc = wid & 3;
    const int lr = lane & 15;
    const int kg = lane >> 4;

    const int sr = tid >> 2;
    const int sc = (tid & 3) * 8;
    const bool rok = (row0 + sr) < M;
    const ushort* Agu = (const ushort*)Aptr + (size_t)(row0 + sr) * lda + sc;
    const ushort* Wg0 = Wt + (size_t)sr * K + sc;

    int4 sa = make_int4(0,0,0,0), sw0 = sa;
    auto load_A = [&](int kk) {
        sa = rok ? *(const int4*)(Agu + kk * 32) : make_int4(0, 0, 0, 0);
    };
    auto load_W = [&](int kk) { sw0 = *(const int4*)(Wg0 + kk * 32); };
    auto store_A = [&](int buf) { *(int4*)&A_s[buf][sr * 40 + sc] = sa; };
    auto store_W = [&](int buf) { *(int4*)&W_s[buf][sr * 40 + sc] = sw0; };

    load_A(0); load_W(0);
    store_A(0); store_W(0);

    f32x4 acc[4][CF];
#pragma unroll
    for (int m = 0; m < 4; ++m)
#pragma unroll
        for (int n = 0; n < CF; ++n) acc[m][n] = (f32x4){0.f, 0.f, 0.f, 0.f};
    float vacc[4] = {0.f, 0.f, 0.f, 0.f};

    const int abase = (wr * 64 + lr) * 40 + kg * 8;

    for (int kk = 0; kk < NK; ++kk) {
        if (kk + 1 < NK) { load_A(kk + 1); load_W(kk + 1); }
        __syncthreads();
        const ushort* Ab = A_s[kk & 1];
        const ushort* Wb = W_s[kk & 1];
        bf16x8 a[4], b[CF];
#pragma unroll
        for (int m = 0; m < 4; ++m) a[m] = *(const bf16x8*)&Ab[abase + m * 16 * 40];
#pragma unroll
        for (int n = 0; n < CF; ++n) {
            const int coln = wc * (NB / 4) + n * 16;
            b[n] = *(const bf16x8*)&Wb[(coln + lr) * 40 + kg * 8];
        }
        if (VH && wc == 0) {
#pragma unroll
            for (int m = 0; m < 4; ++m)
#pragma unroll
                for (int j = 0; j < 8; ++j)
                    vacc[m] += bf2f((ushort)a[m][j]) * wval[kk * 32 + kg * 8 + j];
        }
#pragma unroll
        for (int m = 0; m < 4; ++m)
#pragma unroll
            for (int n = 0; n < CF; ++n)
                acc[m][n] = __builtin_amdgcn_mfma_f32_16x16x32_bf16(a[m], b[n], acc[m][n], 0, 0, 0);
        if (kk + 1 < NK) { store_A((kk + 1) & 1); store_W((kk + 1) & 1); }
    }

    if (VH && wc == 0) {
        const float vb = bg2full[128];
#pragma unroll
        for (int m = 0; m < 4; ++m) {
            float v = vacc[m];
            v += __shfl_xor(v, 16);
            v += __shfl_xor(v, 32);
            if (kg == 0) {
                const int R = row0 + wr * 64 + m * 16 + lr;
                if (R < M) vout[R] = fmaxf(v + vb, 0.f);
            }
        }
    }

#pragma unroll
    for (int m = 0; m < 4; ++m) {
#pragma unroll
        for (int n = 0; n < CF; ++n) {
            const int c = wc * (NB / 4) + n * 16 + lr;
            const float bb = bias[c];
            const int r0 = row0 + wr * 64 + m * 16 + kg * 4;
#pragma unroll
            for (int r = 0; r < 4; ++r) {
                const int R = r0 + r;
                if (R >= M) continue;
                ((float*)Cout)[(size_t)R * ldc + c] = fmaxf(acc[m][n][r] + bb, 0.f);
            }
        }
    }
}

// ---------------- FUSED gemm2+gemm3+reparam, 64-row tiles ------------------
// r19 structure with __launch_bounds__(512, 2): VGPR cap 256 (not 64 as the
// (512,4) bound forced in r19 -> 19 MB spill). LDS ~73 KB -> 2 blocks/CU.
__global__ __launch_bounds__(512, 2) void gemm23_fused64(
    const ushort* __restrict__ Acat, int M,
    const float2* __restrict__ aggra,
    const ushort* __restrict__ Wtg1,      // [256][160]
    const float* __restrict__ bg1,
    const ushort* __restrict__ Whvt,      // [256][256]
    const float* __restrict__ bhv,
    ushort* __restrict__ Hout,            // hidden' ld 128 (dis-prescaled)
    const float* __restrict__ rowscale,
    const float* __restrict__ noise)
{
    __shared__ __align__(16) ushort pool[16896 + 20480];   // X(33KB incl. A alias) + W(40KB)
    ushort* X_s = pool;                 // [64][264]
    ushort* W_s = pool + 16896;         // [2][256*40]

    const int tid  = threadIdx.x;
    const int row0 = blockIdx.x * 64;
    const int lane = tid & 63;
    const int wc   = tid >> 6;          // wave 0..7
    const int lr = lane & 15;
    const int kg = lane >> 4;

    // noise prefetch (consumed in epilogue; issued early to hide HBM latency)
    float nz[16];
    {
        const int c = wc * 16 + lr;
#pragma unroll
        for (int m = 0; m < 4; ++m)
#pragma unroll
            for (int r = 0; r < 4; ++r) {
                const int R = row0 + m * 16 + kg * 4 + r;
                nz[m * 4 + r] = (R < M) ? noise[(size_t)R * 128 + c] : 0.f;
            }
    }

    // staging ids
    const int sa_r = tid >> 2;          // A: threads 0..255 -> rows 0..63
    const int sa_c = (tid & 3) * 8;
    const int sw_r = tid >> 1;          // W: 0..255
    const int sw_c = (tid & 1) * 16;
    const bool arok = (tid < 256) && (row0 + sa_r) < M;
    const ushort* Ap  = Acat + (size_t)(row0 + sa_r) * 128 + sa_c;
    const ushort* W1p = Wtg1 + (size_t)sw_r * 160 + sw_c;
    const ushort* W2p = Whvt + (size_t)sw_r * 256 + sw_c;

    int4 sa = make_int4(0,0,0,0), sw0 = sa, sw1 = sa;
    auto load_A1 = [&](int kk) {
        if (kk == 4) {
            sa = make_int4(0, 0, 0, 0);
            if (sa_c == 0 && arok) {
                const float2 ra = aggra[row0 + sa_r];
                sa.x = packbf(ra.x, ra.y);
            }
        } else {
            sa = arok ? *(const int4*)(Ap + kk * 32) : make_int4(0, 0, 0, 0);
        }
    };
    auto load_W1 = [&](int kk) {
        sw0 = *(const int4*)(W1p + kk * 32);
        sw1 = *(const int4*)(W1p + kk * 32 + 8);
    };
    auto load_W2 = [&](int kk) {
        sw0 = *(const int4*)(W2p + kk * 32);
        sw1 = *(const int4*)(W2p + kk * 32 + 8);
    };
    auto store_A1 = [&](int buf) {
        if (tid < 256) *(int4*)&pool[buf * 2560 + sa_r * 40 + sa_c] = sa;
    };
    auto store_W = [&](int buf) {
        *(int4*)&W_s[buf * 10240 + sw_r * 40 + sw_c] = sw0;
        *(int4*)&W_s[buf * 10240 + sw_r * 40 + sw_c + 8] = sw1;
    };

    // ---- stage 1: x3a[64][256] = relu([aggcat|aggra] @ Wg1 + bg1) ----
    load_A1(0); load_W1(0);
    store_A1(0); store_W(0);

    f32x4 acc1[4][2];
#pragma unroll
    for (int m = 0; m < 4; ++m) {
        acc1[m][0] = (f32x4){0.f, 0.f, 0.f, 0.f};
        acc1[m][1] = (f32x4){0.f, 0.f, 0.f, 0.f};
    }

    for (int kk = 0; kk < 5; ++kk) {
        if (kk + 1 < 5) { load_A1(kk + 1); load_W1(kk + 1); }
        __syncthreads();
        const ushort* Ab = &pool[(kk & 1) * 2560];
        const ushort* Wb = &W_s[(kk & 1) * 10240];
        bf16x8 a[4], b[2];
#pragma unroll
        for (int m = 0; m < 4; ++m) a[m] = *(const bf16x8*)&Ab[(m * 16 + lr) * 40 + kg * 8];
        b[0] = *(const bf16x8*)&Wb[(wc * 32 + lr) * 40 + kg * 8];
        b[1] = *(const bf16x8*)&Wb[(wc * 32 + 16 + lr) * 40 + kg * 8];
#pragma unroll
        for (int m = 0; m < 4; ++m) {
            acc1[m][0] = __builtin_amdgcn_mfma_f32_16x16x32_bf16(a[m], b[0], acc1[m][0], 0, 0, 0);
            acc1[m][1] = __builtin_amdgcn_mfma_f32_16x16x32_bf16(a[m], b[1], acc1[m][1], 0, 0, 0);
        }
        if (kk + 1 < 5) { store_A1((kk + 1) & 1); store_W((kk + 1) & 1); }
    }

    load_W2(0);            // issue stage-2 W slice 0 loads early
    __syncthreads();       // all stage-1 LDS reads done (X aliases A; W buf reuse)

    // x3a -> X_s (bf16, pitch 264)
#pragma unroll
    for (int m = 0; m < 4; ++m) {
#pragma unroll
        for (int n = 0; n < 2; ++n) {
            const int c = wc * 32 + n * 16 + lr;
            const float bb = bg1[c];
#pragma unroll
            for (int r = 0; r < 4; ++r) {
                const int rl = m * 16 + kg * 4 + r;
                X_s[rl * 264 + c] = f2bf(fmaxf(acc1[m][n][r] + bb, 0.f));
            }
        }
    }
    store_W(0);
    __syncthreads();

    // ---- stage 2: K=256 over X_s; mean col = wc*16+lr, logvar col = +128 ----
    f32x4 acc2[4][2];
#pragma unroll
    for (int m = 0; m < 4; ++m) {
        acc2[m][0] = (f32x4){0.f, 0.f, 0.f, 0.f};
        acc2[m][1] = (f32x4){0.f, 0.f, 0.f, 0.f};
    }

    for (int kk = 0; kk < 8; ++kk) {
        if (kk + 1 < 8) load_W2(kk + 1);
        if (kk > 0) __syncthreads();
        const ushort* Wb = &W_s[(kk & 1) * 10240];
        bf16x8 a[4], b[2];
#pragma unroll
        for (int m = 0; m < 4; ++m)
            a[m] = *(const bf16x8*)&X_s[(m * 16 + lr) * 264 + kk * 32 + kg * 8];
        b[0] = *(const bf16x8*)&Wb[(wc * 16 + lr) * 40 + kg * 8];
        b[1] = *(const bf16x8*)&Wb[(128 + wc * 16 + lr) * 40 + kg * 8];
#pragma unroll
        for (int m = 0; m < 4; ++m) {
            acc2[m][0] = __builtin_amdgcn_mfma_f32_16x16x32_bf16(a[m], b[0], acc2[m][0], 0, 0, 0);
            acc2[m][1] = __builtin_amdgcn_mfma_f32_16x16x32_bf16(a[m], b[1], acc2[m][1], 0, 0, 0);
        }
        if (kk + 1 < 8) store_W((kk + 1) & 1);
    }

    // register-only reparam epilogue
    {
        const int c = wc * 16 + lr;
        const float bm = bhv[c];
        const float bl = bhv[c + 128];
#pragma unroll
        for (int m = 0; m < 4; ++m) {
#pragma unroll
            for (int r = 0; r < 4; ++r) {
                const int R = row0 + m * 16 + kg * 4 + r;
                if (R >= M) continue;
                const float mean = fmaxf(acc2[m][0][r] + bm, 0.f);
                const float lv = fmaxf(acc2[m][1][r] + bl, 0.f);
                const float sg = expf(fminf(lv, 5.f));
                Hout[(size_t)R * 128 + c] =
                    f2bf((mean + nz[m * 4 + r] * sg) * rowscale[R]);
            }
        }
    }
}

// ---------------- CSR gather aggregation -----------------------------------
// PRESCALED: h rows already carry dis_i (agg2 path) -> plain adds, final *dd.
// else (agg1): per-edge norm dis[s]*dd, self dd^2 (h written plain by gemm1).
// RA: also aggregate prescaled ra2 pairs (final *dd).
template<bool PRESCALED, bool RA>
__global__ __launch_bounds__(256) void agg128(
    const ushort* __restrict__ h, ushort* __restrict__ out,
    const int* __restrict__ rowptr, const ushort* __restrict__ esrc,
    const float* __restrict__ dis, int n,
    const float2* __restrict__ ra2, float2* __restrict__ aggra)
{
    const int node = (blockIdx.x * blockDim.x + threadIdx.x) >> 6;
    if (node >= n) return;
    const int lane = threadIdx.x & 63;
    const int g = lane >> 4;        // edge group 0..3
    const int sub = lane & 15;      // 8-col chunk
    const float dd = dis[node];

    float acc[8] = {0.f, 0.f, 0.f, 0.f, 0.f, 0.f, 0.f, 0.f};
    float ra_a = 0.f, ra_b = 0.f;
    if (g == 0) {   // self term
        const int4 v = *(const int4*)(h + (size_t)node * 128 + sub * 8);
        if (PRESCALED) acc_add(acc, v);
        else           acc_mad(acc, v, dd * dd);
        if (RA && sub == 0) { const float2 f = ra2[node]; ra_a = f.x; ra_b = f.y; }
    }
    const int b = rowptr[node];
    const int m = rowptr[node + 1] - b;
    int j = b + ((m * g) >> 2);
    const int q1 = b + ((m * (g + 1)) >> 2);
    for (; j + 3 < q1; j += 4) {
        const int s0 = (int)esrc[j],     s1 = (int)esrc[j + 1];
        const int s2 = (int)esrc[j + 2], s3 = (int)esrc[j + 3];
        const int4 v0 = *(const int4*)(h + (size_t)s0 * 128 + sub * 8);
        const int4 v1 = *(const int4*)(h + (size_t)s1 * 128 + sub * 8);
        const int4 v2 = *(const int4*)(h + (size_t)s2 * 128 + sub * 8);
        const int4 v3 = *(const int4*)(h + (size_t)s3 * 128 + sub * 8);
        if (PRESCALED) {
            acc_add(acc, v0); acc_add(acc, v1); acc_add(acc, v2); acc_add(acc, v3);
        } else {
            acc_mad(acc, v0, dis[s0] * dd); acc_mad(acc, v1, dis[s1] * dd);
            acc_mad(acc, v2, dis[s2] * dd); acc_mad(acc, v3, dis[s3] * dd);
        }
        if (RA && sub == 0) {
            const float2 f0 = ra2[s0], f1 = ra2[s1], f2 = ra2[s2], f3 = ra2[s3];
            ra_a += f0.x + f1.x + f2.x + f3.x;
            ra_b += f0.y + f1.y + f2.y + f3.y;
        }
    }
    for (; j < q1; ++j) {
        const int s0 = (int)esrc[j];
        const int4 v0 = *(const int4*)(h + (size_t)s0 * 128 + sub * 8);
        if (PRESCALED) acc_add(acc, v0);
        else           acc_mad(acc, v0, dis[s0] * dd);
        if (RA && sub == 0) { const float2 f = ra2[s0]; ra_a += f.x; ra_b += f.y; }
    }
#pragma unroll
    for (int i = 0; i < 8; ++i) {
        acc[i] += __shfl_xor(acc[i], 16);
        acc[i] += __shfl_xor(acc[i], 32);
    }
    if (RA) {
        ra_a += __shfl_xor(ra_a, 16); ra_a += __shfl_xor(ra_a, 32);
        ra_b += __shfl_xor(ra_b, 16); ra_b += __shfl_xor(ra_b, 32);
        if (lane == 0) aggra[node] = make_float2(dd * ra_a, dd * ra_b);
    }
    if (g == 0) {
        const float s = PRESCALED ? dd : 1.0f;
        int4 r;
        r.x = packbf(s * acc[0], s * acc[1]);
        r.y = packbf(s * acc[2], s * acc[3]);
        r.z = packbf(s * acc[4], s * acc[5]);
        r.w = packbf(s * acc[6], s * acc[7]);
        *(int4*)(out + (size_t)node * 128 + sub * 8) = r;
    }
}

extern "C" void kernel_launch(void* const* d_in, const int* in_sizes, int n_in,
                              void* d_out, int out_size, void* d_ws, size_t ws_size,
                              hipStream_t stream)
{
    const float* x      = (const float*)d_in[0];
    const float* rw1    = (const float*)d_in[1];
    const float* action = (const float*)d_in[2];
    const float* noise  = (const float*)d_in[3];
    const int*   eidx   = (const int*)d_in[4];
    const float* W1     = (const float*)d_in[5];
    const float* b1     = (const float*)d_in[6];
    const float* Wg1    = (const float*)d_in[7];
    const float* bg1    = (const float*)d_in[8];
    const float* Whv    = (const float*)d_in[9];
    const float* bhv    = (const float*)d_in[10];
    const float* Wg2    = (const float*)d_in[11];
    const float* bg2    = (const float*)d_in[12];
    const int* src = eidx;
    const int* dst = eidx + NE;

    // Regions (u16 units), 12.8M each:
    // R0: edge staging (6.4MB, dies after sort)   R1: h -> hidden' (ld 128)
    // R2: unused spare                            R3: aggcat -> agghid (ld 128)
    ushort* R0 = (ushort*)d_ws;
    ushort* R1 = R0 + 12800000;
    ushort* R2 = R1 + 12800000;
    ushort* R3 = R2 + 12800000;
    unsigned* staging = (unsigned*)R0;
    float* dis  = (float*)(R3 + 12800000);
    int* rowptr = (int*)(dis + NN);              // NN+1
    ushort* esrc = (ushort*)(rowptr + NN + 4);   // u16 src ids
    ushort* Wt1  = esrc + NE;              // [128][256]
    ushort* Wtg1 = Wt1 + 128 * 256;        // [256][160]
    ushort* Whvt = Wtg1 + 256 * 160;       // [256][256]
    ushort* Wg2t = Whvt + 256 * 256;       // [128][128]
    float* wval  = (float*)(Wg2t + 128 * 128);   // [128]
    float2* aggra = (float2*)(wval + 128);       // [NN]
    float2* ra2   = aggra + NN;                  // [NN] prescaled (rw,act)
    int* bcur   = (int*)(ra2 + NN);              // [NBUCK]

    const int T = 256;
    const int gemmRows = (NN + 127) / 128;       // 391
    const int gemm64Rows = (NN + 63) / 64;       // 782
    const int bucketBlocks = (NE + 2047) / 2048; // 391
    const int aggBlocks = (NN + 3) / 4;

    // ---- prep: weight transposes + bcur zero ----
    transpose_all<<<611, T, 0, stream>>>(W1, Wg1, Whv, Wg2, Wt1, Wtg1, Whvt, Wg2t,
                                         wval, bcur);

    // ---- COMBINED gemm1 (h plain bf16) + bucket_edges (independent) ----
    gemm1_bucket<<<gemmRows + bucketBlocks, 512, 0, stream>>>(
        x, Wt1, b1, R1, NN, gemmRows, src, dst, bcur, staging, NE);

    // ---- sort buckets -> rowptr/dis/ra2/esrc ----
    sort_bucket<<<NBUCK, 128, 0, stream>>>(staging, bcur, rowptr, dis, ra2,
                                           rw1, action, esrc, NN, NE);

    // ---- agg1 (per-edge norm) on h -> aggcat (R3) + rw/action -> aggra ----
    agg128<false, true><<<aggBlocks, T, 0, stream>>>(
        R1, R3, rowptr, esrc, dis, NN, ra2, aggra);

    // ---- FUSED gemm2+gemm3+reparam (64-row, 2 blocks/CU): hidden' -> R1 ----
    gemm23_fused64<<<gemm64Rows, 512, 0, stream>>>(
        R3, NN, aggra, Wtg1, bg1, Whvt, bhv, R1, dis, noise);

    // ---- agg2 (prescaled) on hidden' -> agghid (R3) ----
    agg128<true, false><<<aggBlocks, T, 0, stream>>>(
        R1, R3, rowptr, esrc, dis, NN, nullptr, nullptr);

    // ---- gemm4 + fused value head: cols -> d_out f32, val -> d_out tail ----
    gemm_mfma<128, 128, true><<<gemmRows, 512, 0, stream>>>(
        R3, 128, NN, Wg2t, bg2, d_out, 128,
        wval, bg2, (float*)d_out + (size_t)NN * 128);
}

// Round 22
// 176.306 us; speedup vs baseline: 1.0440x; 1.0440x over previous
//
#include <hip/hip_runtime.h>

static constexpr int NN = 50000;   // nodes
static constexpr int NE = 800000;  // edges
static constexpr int NBUCK = (NN + 127) / 128;  // 391 buckets (dst >> 7)
static constexpr int CAP = 4096;   // staging capacity per bucket

typedef __attribute__((ext_vector_type(8))) short bf16x8;
typedef __attribute__((ext_vector_type(4))) float f32x4;

__device__ __forceinline__ float bf2f(ushort u) {
    union { unsigned int i; float f; } c; c.i = ((unsigned int)u) << 16; return c.f;
}
__device__ __forceinline__ ushort f2bf(float f) {
    union { float f; unsigned int i; } c; c.f = f;
    unsigned int x = c.i;
    return (ushort)((x + 0x7FFFu + ((x >> 16) & 1u)) >> 16);
}
__device__ __forceinline__ int packbf(float a, float b) {
    return (int)f2bf(a) | ((int)f2bf(b) << 16);
}
__device__ __forceinline__ void acc_add(float* acc, const int4 v) {
    acc[0] += bf2f((ushort)(v.x & 0xffff));
    acc[1] += bf2f((ushort)((unsigned)v.x >> 16));
    acc[2] += bf2f((ushort)(v.y & 0xffff));
    acc[3] += bf2f((ushort)((unsigned)v.y >> 16));
    acc[4] += bf2f((ushort)(v.z & 0xffff));
    acc[5] += bf2f((ushort)((unsigned)v.z >> 16));
    acc[6] += bf2f((ushort)(v.w & 0xffff));
    acc[7] += bf2f((ushort)((unsigned)v.w >> 16));
}
__device__ __forceinline__ void acc_mad(float* acc, const int4 v, const float s) {
    acc[0] += bf2f((ushort)(v.x & 0xffff)) * s;
    acc[1] += bf2f((ushort)((unsigned)v.x >> 16)) * s;
    acc[2] += bf2f((ushort)(v.y & 0xffff)) * s;
    acc[3] += bf2f((ushort)((unsigned)v.y >> 16)) * s;
    acc[4] += bf2f((ushort)(v.z & 0xffff)) * s;
    acc[5] += bf2f((ushort)((unsigned)v.z >> 16)) * s;
    acc[6] += bf2f((ushort)(v.w & 0xffff)) * s;
    acc[7] += bf2f((ushort)((unsigned)v.w >> 16)) * s;
}

// ---------------- prep: weight transposes + bcur zero ----------------
__global__ void transpose_all(const float* __restrict__ W1, const float* __restrict__ Wg1,
                              const float* __restrict__ Whv, const float* __restrict__ Wg2,
                              ushort* __restrict__ Wt1, ushort* __restrict__ Wtg1,
                              ushort* __restrict__ Whvt, ushort* __restrict__ Wg2t,
                              float* __restrict__ wval, int* __restrict__ bcur)
{
    int idx = blockIdx.x * blockDim.x + threadIdx.x;
    if (idx < 128 * 256) {                 // Wt1 [128][256] <- W1 [256][128]
        const int n = idx >> 8, k = idx & 255;
        Wt1[idx] = f2bf(W1[k * 128 + n]);
        return;
    }
    idx -= 128 * 256;
    if (idx < 256 * 160) {                 // Wtg1 [256][160] <- Wg1 [130][256]
        const int n = idx / 160, k = idx - n * 160;
        Wtg1[idx] = (k < 130) ? f2bf(Wg1[k * 256 + n]) : (ushort)0;
        return;
    }
    idx -= 256 * 160;
    if (idx < 256 * 256) {                 // Whvt [256][256] <- Whv [256][256]
        const int n = idx >> 8, k = idx & 255;
        Whvt[idx] = f2bf(Whv[k * 256 + n]);
        return;
    }
    idx -= 256 * 256;
    if (idx < 128 * 128) {                 // Wg2t [128][128] <- Wg2 [128][129] cols 0..127
        const int n = idx >> 7, k = idx & 127;
        Wg2t[idx] = f2bf(Wg2[k * 129 + n]);
        return;
    }
    idx -= 128 * 128;
    if (idx < 128) { wval[idx] = Wg2[idx * 129 + 128]; return; }
    idx -= 128;
    if (idx < NBUCK) bcur[idx] = 0;
}

// ---------------- COMBINED: gemm1 (blocks < gemmBlocks) + bucket_edges -----
// gemm1: h = relu(x@W1+b1) plain bf16 (no dis prescale; dis not yet computed).
// bucket: partition edges into dst-buckets (independent of gemm1).
__global__ __launch_bounds__(512) void gemm1_bucket(
    const float* __restrict__ x, const ushort* __restrict__ Wt1,
    const float* __restrict__ b1, ushort* __restrict__ h, int M, int gemmBlocks,
    const int* __restrict__ src, const int* __restrict__ dst,
    int* __restrict__ bcur, unsigned* __restrict__ staging, int e)
{
    __shared__ __align__(16) ushort pool[20480];   // 40 KB

    if (blockIdx.x >= gemmBlocks) {
        // ---------------- bucket_edges (512 threads) ----------------
        int* bins  = (int*)pool;
        int* gbase = bins + NBUCK;
        int* cur   = gbase + NBUCK;
        const int t = threadIdx.x;
        const int base = (blockIdx.x - gemmBlocks) * 2048;
        for (int i = t; i < NBUCK; i += 512) bins[i] = 0;
        __syncthreads();
        const int lim = min(2048, e - base);
        for (int i = t; i < lim; i += 512)
            atomicAdd(&bins[dst[base + i] >> 7], 1);
        __syncthreads();
        for (int i = t; i < NBUCK; i += 512) {
            cur[i] = 0;
            gbase[i] = bins[i] ? atomicAdd(&bcur[i], bins[i]) : 0;
        }
        __syncthreads();
        for (int i = t; i < lim; i += 512) {
            const int d = dst[base + i];
            const int b = d >> 7;
            const int r = atomicAdd(&cur[b], 1);
            staging[(size_t)b * CAP + gbase[b] + r] =
                ((unsigned)(d & 127) << 16) | (unsigned)src[base + i];
        }
        return;
    }

    // ---------------- gemm1: K=256, NB=128, A f32 cast-on-stage ----------------
    ushort* A_s = pool;             // [2][128*40] = 10240
    ushort* W_s = pool + 10240;     // [2][128*40]

    const int tid  = threadIdx.x;
    const int row0 = blockIdx.x * 128;
    const int lane = tid & 63;
    const int wid  = tid >> 6;
    const int wr = wid >> 2;
    const int wc = wid & 3;
    const int lr = lane & 15;
    const int kg = lane >> 4;

    const int sr = tid >> 2;
    const int sc = (tid & 3) * 8;
    const bool rok = (row0 + sr) < M;
    const float* Agf = x + (size_t)(row0 + sr) * 256 + sc;
    const ushort* Wg0 = Wt1 + (size_t)sr * 256 + sc;

    int4 sa = make_int4(0,0,0,0), sw0 = sa;
    auto load_A = [&](int kk) {
        if (rok) {
            const float* p = Agf + kk * 32;
            const float4 f0 = *(const float4*)(p + 0);
            const float4 f1 = *(const float4*)(p + 4);
            sa.x = packbf(f0.x, f0.y); sa.y = packbf(f0.z, f0.w);
            sa.z = packbf(f1.x, f1.y); sa.w = packbf(f1.z, f1.w);
        } else sa = make_int4(0, 0, 0, 0);
    };
    auto load_W = [&](int kk) { sw0 = *(const int4*)(Wg0 + kk * 32); };
    auto store_A = [&](int buf) { *(int4*)&A_s[buf * 5120 + sr * 40 + sc] = sa; };
    auto store_W = [&](int buf) { *(int4*)&W_s[buf * 5120 + sr * 40 + sc] = sw0; };

    load_A(0); load_W(0);
    store_A(0); store_W(0);

    f32x4 acc[4][2];
#pragma unroll
    for (int m = 0; m < 4; ++m) {
        acc[m][0] = (f32x4){0.f, 0.f, 0.f, 0.f};
        acc[m][1] = (f32x4){0.f, 0.f, 0.f, 0.f};
    }

    const int abase = (wr * 64 + lr) * 40 + kg * 8;

    for (int kk = 0; kk < 8; ++kk) {
        if (kk + 1 < 8) { load_A(kk + 1); load_W(kk + 1); }
        __syncthreads();
        const ushort* Ab = &A_s[(kk & 1) * 5120];
        const ushort* Wb = &W_s[(kk & 1) * 5120];
        bf16x8 a[4], b[2];
#pragma unroll
        for (int m = 0; m < 4; ++m) a[m] = *(const bf16x8*)&Ab[abase + m * 16 * 40];
        b[0] = *(const bf16x8*)&Wb[(wc * 32 + lr) * 40 + kg * 8];
        b[1] = *(const bf16x8*)&Wb[(wc * 32 + 16 + lr) * 40 + kg * 8];
#pragma unroll
        for (int m = 0; m < 4; ++m) {
            acc[m][0] = __builtin_amdgcn_mfma_f32_16x16x32_bf16(a[m], b[0], acc[m][0], 0, 0, 0);
            acc[m][1] = __builtin_amdgcn_mfma_f32_16x16x32_bf16(a[m], b[1], acc[m][1], 0, 0, 0);
        }
        if (kk + 1 < 8) { store_A((kk + 1) & 1); store_W((kk + 1) & 1); }
    }

#pragma unroll
    for (int m = 0; m < 4; ++m) {
#pragma unroll
        for (int n = 0; n < 2; ++n) {
            const int c = wc * 32 + n * 16 + lr;
            const float bb = b1[c];
            const int r0 = row0 + wr * 64 + m * 16 + kg * 4;
#pragma unroll
            for (int r = 0; r < 4; ++r) {
                const int R = r0 + r;
                if (R >= M) continue;
                h[(size_t)R * 128 + c] = f2bf(fmaxf(acc[m][n][r] + bb, 0.f));
            }
        }
    }
}

// per-bucket counting sort; computes its own bucket prefix (no separate scan);
// emits rowptr, dis, prescaled ra2, and coalesced esrc.
__global__ __launch_bounds__(128) void sort_bucket(
    const unsigned* __restrict__ staging, const int* __restrict__ bcur,
    int* __restrict__ rowptr, float* __restrict__ dis, float2* __restrict__ ra2,
    const float* __restrict__ rw1, const float* __restrict__ act,
    ushort* __restrict__ esrc, int n, int e)
{
    __shared__ int bins[128];
    __shared__ int sdata[128];
    __shared__ int baseSh;
    __shared__ ushort outb[CAP];
    const int b = blockIdx.x;
    const int t = threadIdx.x;

    // ---- own prefix: base = sum(bcur[0..b)) ----
    int part = 0;
    for (int i = t; i < b; i += 128) part += bcur[i];
    sdata[t] = part;
    bins[t] = 0;
    __syncthreads();
#pragma unroll
    for (int off = 64; off > 0; off >>= 1) {
        if (t < off) sdata[t] += sdata[t + off];
        __syncthreads();
    }
    if (t == 0) baseSh = sdata[0];
    __syncthreads();
    const int base = baseSh;

    // ---- histogram ----
    const int m = bcur[b];
    const unsigned* sp = staging + (size_t)b * CAP;
    for (int i = t; i < m; i += 128) atomicAdd(&bins[sp[i] >> 16], 1);
    __syncthreads();
    const int v = bins[t];
    sdata[t] = v;
    __syncthreads();
#pragma unroll
    for (int off = 1; off < 128; off <<= 1) {
        const int u = (t >= off) ? sdata[t - off] : 0;
        __syncthreads();
        sdata[t] += u;
        __syncthreads();
    }
    const int excl = sdata[t] - v;
    bins[t] = excl;   // cursor
    const int node = (b << 7) + t;
    if (node < n) {
        rowptr[node] = base + excl;
        const float d = rsqrtf(1.0f + (float)v);
        dis[node] = d;
        ra2[node] = make_float2(rw1[node] * d, act[node] * d);
    }
    if (b == 0 && t == 0) rowptr[n] = e;
    __syncthreads();
    for (int i = t; i < m; i += 128) {
        const unsigned p = sp[i];
        const int r = atomicAdd(&bins[p >> 16], 1);
        outb[r] = (ushort)(p & 0xffffu);
    }
    __syncthreads();
    for (int i = t; i < m; i += 128) esrc[base + i] = outb[i];
}

// ---------------- bf16 MFMA GEMM (gemm4 only) -------------------------------
// VH: fused value head — wc==0 waves dot A rows with wval during the K-loop.
template<int K, int NB, bool VH>
__global__ __launch_bounds__(512) void gemm_mfma(
    const void* __restrict__ Aptr, int lda, int M,
    const ushort* __restrict__ Wt,
    const float* __restrict__ bias,
    void* __restrict__ Cout, int ldc,
    const float* __restrict__ wval, const float* __restrict__ bg2full,
    float* __restrict__ vout)
{
    constexpr int NK = K / 32;
    constexpr int CF = NB / 64;
    __shared__ ushort A_s[2][128 * 40];
    __shared__ ushort W_s[2][NB * 40];

    const int tid  = threadIdx.x;
    const int row0 = blockIdx.x * 128;
    const int lane = tid & 63;
    const int wid  = tid >> 6;
    const int wr = wid >> 2;
    const int wc = wid & 3;
    const int lr = lane & 15;
    const int kg = lane >> 4;

    const int sr = tid >> 2;
    const int sc = (tid & 3) * 8;
    const bool rok = (row0 + sr) < M;
    const ushort* Agu = (const ushort*)Aptr + (size_t)(row0 + sr) * lda + sc;
    const ushort* Wg0 = Wt + (size_t)sr * K + sc;

    int4 sa = make_int4(0,0,0,0), sw0 = sa;
    auto load_A = [&](int kk) {
        sa = rok ? *(const int4*)(Agu + kk * 32) : make_int4(0, 0, 0, 0);
    };
    auto load_W = [&](int kk) { sw0 = *(const int4*)(Wg0 + kk * 32); };
    auto store_A = [&](int buf) { *(int4*)&A_s[buf][sr * 40 + sc] = sa; };
    auto store_W = [&](int buf) { *(int4*)&W_s[buf][sr * 40 + sc] = sw0; };

    load_A(0); load_W(0);
    store_A(0); store_W(0);

    f32x4 acc[4][CF];
#pragma unroll
    for (int m = 0; m < 4; ++m)
#pragma unroll
        for (int n = 0; n < CF; ++n) acc[m][n] = (f32x4){0.f, 0.f, 0.f, 0.f};
    float vacc[4] = {0.f, 0.f, 0.f, 0.f};

    const int abase = (wr * 64 + lr) * 40 + kg * 8;

    for (int kk = 0; kk < NK; ++kk) {
        if (kk + 1 < NK) { load_A(kk + 1); load_W(kk + 1); }
        __syncthreads();
        const ushort* Ab = A_s[kk & 1];
        const ushort* Wb = W_s[kk & 1];
        bf16x8 a[4], b[CF];
#pragma unroll
        for (int m = 0; m < 4; ++m) a[m] = *(const bf16x8*)&Ab[abase + m * 16 * 40];
#pragma unroll
        for (int n = 0; n < CF; ++n) {
            const int coln = wc * (NB / 4) + n * 16;
            b[n] = *(const bf16x8*)&Wb[(coln + lr) * 40 + kg * 8];
        }
        if (VH && wc == 0) {
#pragma unroll
            for (int m = 0; m < 4; ++m)
#pragma unroll
                for (int j = 0; j < 8; ++j)
                    vacc[m] += bf2f((ushort)a[m][j]) * wval[kk * 32 + kg * 8 + j];
        }
#pragma unroll
        for (int m = 0; m < 4; ++m)
#pragma unroll
            for (int n = 0; n < CF; ++n)
                acc[m][n] = __builtin_amdgcn_mfma_f32_16x16x32_bf16(a[m], b[n], acc[m][n], 0, 0, 0);
        if (kk + 1 < NK) { store_A((kk + 1) & 1); store_W((kk + 1) & 1); }
    }

    if (VH && wc == 0) {
        const float vb = bg2full[128];
#pragma unroll
        for (int m = 0; m < 4; ++m) {
            float v = vacc[m];
            v += __shfl_xor(v, 16);
            v += __shfl_xor(v, 32);
            if (kg == 0) {
                const int R = row0 + wr * 64 + m * 16 + lr;
                if (R < M) vout[R] = fmaxf(v + vb, 0.f);
            }
        }
    }

#pragma unroll
    for (int m = 0; m < 4; ++m) {
#pragma unroll
        for (int n = 0; n < CF; ++n) {
            const int c = wc * (NB / 4) + n * 16 + lr;
            const float bb = bias[c];
            const int r0 = row0 + wr * 64 + m * 16 + kg * 4;
#pragma unroll
            for (int r = 0; r < 4; ++r) {
                const int R = r0 + r;
                if (R >= M) continue;
                ((float*)Cout)[(size_t)R * ldc + c] = fmaxf(acc[m][n][r] + bb, 0.f);
            }
        }
    }
}

// ---------------- FUSED gemm2+gemm3+reparam (r16 proven version) -----------
// Stage 1: x3a[128][256] = relu([aggcat|aggra] @ Wg1 + bg1) -> LDS (bf16, 264)
// Stage 2: tmp = x3a @ Whv + bhv (K=256, Whv K-slices dbuf'd from global);
//          register-only reparam -> hidden' = (mean + noise*sigma)*dis.
__global__ __launch_bounds__(512, 2) void gemm23_fused(
    const ushort* __restrict__ Acat, int M,
    const float2* __restrict__ aggra,
    const ushort* __restrict__ Wtg1,      // [256][160]
    const float* __restrict__ bg1,
    const ushort* __restrict__ Whvt,      // [256][256]
    const float* __restrict__ bhv,
    ushort* __restrict__ Hout,            // hidden' ld 128
    const float* __restrict__ rowscale,
    const float* __restrict__ noise)
{
    __shared__ ushort A_s[2][128 * 40];   // 20 KB
    __shared__ ushort W_s[2][256 * 40];   // 40 KB
    __shared__ ushort X_s[128 * 264];     // 66 KB x3a

    const int tid  = threadIdx.x;
    const int row0 = blockIdx.x * 128;
    const int lane = tid & 63;
    const int wid  = tid >> 6;
    const int wr = wid >> 2;
    const int wc = wid & 3;
    const int lr = lane & 15;
    const int kg = lane >> 4;

    // ---- stage 1: K=160, NB=256 ----
    const int sr = tid >> 2;
    const int sc = (tid & 3) * 8;
    const bool rok = (row0 + sr) < M;
    const ushort* Agu = Acat + (size_t)(row0 + sr) * 128 + sc;
    const ushort* Wg0 = Wtg1 + (size_t)sr * 160 + sc;
    const ushort* Wg1p = Wtg1 + (size_t)(sr + 128) * 160 + sc;

    int4 sa = make_int4(0,0,0,0), sw0 = sa, sw1 = sa;
    auto load_A1 = [&](int kk) {
        if (kk == 4) {
            sa = make_int4(0, 0, 0, 0);
            if (sc == 0 && rok) {
                const float2 ra = aggra[row0 + sr];
                sa.x = packbf(ra.x, ra.y);
            }
        } else {
            sa = rok ? *(const int4*)(Agu + kk * 32) : make_int4(0, 0, 0, 0);
        }
    };
    auto load_W1 = [&](int kk) {
        sw0 = *(const int4*)(Wg0 + kk * 32);
        sw1 = *(const int4*)(Wg1p + kk * 32);
    };
    auto store_A1 = [&](int buf) { *(int4*)&A_s[buf][sr * 40 + sc] = sa; };
    auto store_W1 = [&](int buf) {
        *(int4*)&W_s[buf][sr * 40 + sc] = sw0;
        *(int4*)&W_s[buf][(sr + 128) * 40 + sc] = sw1;
    };

    load_A1(0); load_W1(0);
    store_A1(0); store_W1(0);

    f32x4 acc1[4][4];
#pragma unroll
    for (int m = 0; m < 4; ++m)
#pragma unroll
        for (int n = 0; n < 4; ++n) acc1[m][n] = (f32x4){0.f, 0.f, 0.f, 0.f};

    const int abase = (wr * 64 + lr) * 40 + kg * 8;

    for (int kk = 0; kk < 5; ++kk) {
        if (kk + 1 < 5) { load_A1(kk + 1); load_W1(kk + 1); }
        __syncthreads();
        const ushort* Ab = A_s[kk & 1];
        const ushort* Wb = W_s[kk & 1];
        bf16x8 a[4], b[4];
#pragma unroll
        for (int m = 0; m < 4; ++m) a[m] = *(const bf16x8*)&Ab[abase + m * 16 * 40];
#pragma unroll
        for (int n = 0; n < 4; ++n)
            b[n] = *(const bf16x8*)&Wb[(wc * 64 + n * 16 + lr) * 40 + kg * 8];
#pragma unroll
        for (int m = 0; m < 4; ++m)
#pragma unroll
            for (int n = 0; n < 4; ++n)
                acc1[m][n] = __builtin_amdgcn_mfma_f32_16x16x32_bf16(a[m], b[n], acc1[m][n], 0, 0, 0);
        if (kk + 1 < 5) { store_A1((kk + 1) & 1); store_W1((kk + 1) & 1); }
    }

    // x3a -> LDS (bf16, pitch 264)
#pragma unroll
    for (int m = 0; m < 4; ++m) {
#pragma unroll
        for (int n = 0; n < 4; ++n) {
            const int c = wc * 64 + n * 16 + lr;
            const float bb = bg1[c];
#pragma unroll
            for (int r = 0; r < 4; ++r) {
                const int rl = wr * 64 + m * 16 + kg * 4 + r;
                X_s[rl * 264 + c] = f2bf(fmaxf(acc1[m][n][r] + bb, 0.f));
            }
        }
    }
    __syncthreads();

    // ---- stage 2: K=256 over X_s; Whv slices dbuf'd through W_s ----
    float nz[2][16];
#pragma unroll
    for (int n = 0; n < 2; ++n) {
        const int c = wc * 32 + n * 16 + lr;
#pragma unroll
        for (int m = 0; m < 4; ++m)
#pragma unroll
            for (int r = 0; r < 4; ++r) {
                const int R = row0 + wr * 64 + m * 16 + kg * 4 + r;
                nz[n][m * 4 + r] = (R < M) ? noise[(size_t)R * 128 + c] : 0.f;
            }
    }

    const int sr2 = tid >> 1;
    const int sc2 = (tid & 1) * 16;
    const ushort* Wg2p = Whvt + (size_t)sr2 * 256 + sc2;
    int4 t0, t1;
    auto load_W2 = [&](int kk) {
        t0 = *(const int4*)(Wg2p + kk * 32);
        t1 = *(const int4*)(Wg2p + kk * 32 + 8);
    };
    auto store_W2 = [&](int buf) {
        *(int4*)&W_s[buf][sr2 * 40 + sc2] = t0;
        *(int4*)&W_s[buf][sr2 * 40 + sc2 + 8] = t1;
    };

    load_W2(0);
    store_W2(0);

    f32x4 acc2[4][4];
#pragma unroll
    for (int m = 0; m < 4; ++m)
#pragma unroll
        for (int n = 0; n < 4; ++n) acc2[m][n] = (f32x4){0.f, 0.f, 0.f, 0.f};

    for (int kk = 0; kk < 8; ++kk) {
        if (kk + 1 < 8) load_W2(kk + 1);
        __syncthreads();
        const ushort* Wb = W_s[kk & 1];
        bf16x8 a[4], b[4];
#pragma unroll
        for (int m = 0; m < 4; ++m)
            a[m] = *(const bf16x8*)&X_s[(wr * 64 + m * 16 + lr) * 264 + kk * 32 + kg * 8];
        b[0] = *(const bf16x8*)&Wb[(wc * 32 + lr) * 40 + kg * 8];
        b[1] = *(const bf16x8*)&Wb[(wc * 32 + 16 + lr) * 40 + kg * 8];
        b[2] = *(const bf16x8*)&Wb[(128 + wc * 32 + lr) * 40 + kg * 8];
        b[3] = *(const bf16x8*)&Wb[(128 + wc * 32 + 16 + lr) * 40 + kg * 8];
#pragma unroll
        for (int m = 0; m < 4; ++m)
#pragma unroll
            for (int n = 0; n < 4; ++n)
                acc2[m][n] = __builtin_amdgcn_mfma_f32_16x16x32_bf16(a[m], b[n], acc2[m][n], 0, 0, 0);
        if (kk + 1 < 8) store_W2((kk + 1) & 1);
    }

    // register-only reparam epilogue
#pragma unroll
    for (int n = 0; n < 2; ++n) {
        const int c = wc * 32 + n * 16 + lr;
        const float bm = bhv[c];
        const float bl = bhv[c + 128];
#pragma unroll
        for (int m = 0; m < 4; ++m) {
#pragma unroll
            for (int r = 0; r < 4; ++r) {
                const int R = row0 + wr * 64 + m * 16 + kg * 4 + r;
                if (R >= M) continue;
                const float mean = fmaxf(acc2[m][n][r] + bm, 0.f);
                const float lv = fmaxf(acc2[m][n + 2][r] + bl, 0.f);
                const float sg = expf(fminf(lv, 5.f));
                Hout[(size_t)R * 128 + c] =
                    f2bf((mean + nz[n][m * 4 + r] * sg) * rowscale[R]);
            }
        }
    }
}

// ---------------- CSR gather aggregation -----------------------------------
// PRESCALED: h rows already carry dis_i (agg2 path) -> plain adds, final *dd.
// else (agg1): per-edge norm dis[s]*dd, self dd^2 (h written plain by gemm1).
// RA: also aggregate prescaled ra2 pairs (final *dd).
template<bool PRESCALED, bool RA>
__global__ __launch_bounds__(256) void agg128(
    const ushort* __restrict__ h, ushort* __restrict__ out,
    const int* __restrict__ rowptr, const ushort* __restrict__ esrc,
    const float* __restrict__ dis, int n,
    const float2* __restrict__ ra2, float2* __restrict__ aggra)
{
    const int node = (blockIdx.x * blockDim.x + threadIdx.x) >> 6;
    if (node >= n) return;
    const int lane = threadIdx.x & 63;
    const int g = lane >> 4;        // edge group 0..3
    const int sub = lane & 15;      // 8-col chunk
    const float dd = dis[node];

    float acc[8] = {0.f, 0.f, 0.f, 0.f, 0.f, 0.f, 0.f, 0.f};
    float ra_a = 0.f, ra_b = 0.f;
    if (g == 0) {   // self term
        const int4 v = *(const int4*)(h + (size_t)node * 128 + sub * 8);
        if (PRESCALED) acc_add(acc, v);
        else           acc_mad(acc, v, dd * dd);
        if (RA && sub == 0) { const float2 f = ra2[node]; ra_a = f.x; ra_b = f.y; }
    }
    const int b = rowptr[node];
    const int m = rowptr[node + 1] - b;
    int j = b + ((m * g) >> 2);
    const int q1 = b + ((m * (g + 1)) >> 2);
    for (; j + 3 < q1; j += 4) {
        const int s0 = (int)esrc[j],     s1 = (int)esrc[j + 1];
        const int s2 = (int)esrc[j + 2], s3 = (int)esrc[j + 3];
        const int4 v0 = *(const int4*)(h + (size_t)s0 * 128 + sub * 8);
        const int4 v1 = *(const int4*)(h + (size_t)s1 * 128 + sub * 8);
        const int4 v2 = *(const int4*)(h + (size_t)s2 * 128 + sub * 8);
        const int4 v3 = *(const int4*)(h + (size_t)s3 * 128 + sub * 8);
        if (PRESCALED) {
            acc_add(acc, v0); acc_add(acc, v1); acc_add(acc, v2); acc_add(acc, v3);
        } else {
            acc_mad(acc, v0, dis[s0] * dd); acc_mad(acc, v1, dis[s1] * dd);
            acc_mad(acc, v2, dis[s2] * dd); acc_mad(acc, v3, dis[s3] * dd);
        }
        if (RA && sub == 0) {
            const float2 f0 = ra2[s0], f1 = ra2[s1], f2 = ra2[s2], f3 = ra2[s3];
            ra_a += f0.x + f1.x + f2.x + f3.x;
            ra_b += f0.y + f1.y + f2.y + f3.y;
        }
    }
    for (; j < q1; ++j) {
        const int s0 = (int)esrc[j];
        const int4 v0 = *(const int4*)(h + (size_t)s0 * 128 + sub * 8);
        if (PRESCALED) acc_add(acc, v0);
        else           acc_mad(acc, v0, dis[s0] * dd);
        if (RA && sub == 0) { const float2 f = ra2[s0]; ra_a += f.x; ra_b += f.y; }
    }
#pragma unroll
    for (int i = 0; i < 8; ++i) {
        acc[i] += __shfl_xor(acc[i], 16);
        acc[i] += __shfl_xor(acc[i], 32);
    }
    if (RA) {
        ra_a += __shfl_xor(ra_a, 16); ra_a += __shfl_xor(ra_a, 32);
        ra_b += __shfl_xor(ra_b, 16); ra_b += __shfl_xor(ra_b, 32);
        if (lane == 0) aggra[node] = make_float2(dd * ra_a, dd * ra_b);
    }
    if (g == 0) {
        const float s = PRESCALED ? dd : 1.0f;
        int4 r;
        r.x = packbf(s * acc[0], s * acc[1]);
        r.y = packbf(s * acc[2], s * acc[3]);
        r.z = packbf(s * acc[4], s * acc[5]);
        r.w = packbf(s * acc[6], s * acc[7]);
        *(int4*)(out + (size_t)node * 128 + sub * 8) = r;
    }
}

extern "C" void kernel_launch(void* const* d_in, const int* in_sizes, int n_in,
                              void* d_out, int out_size, void* d_ws, size_t ws_size,
                              hipStream_t stream)
{
    const float* x      = (const float*)d_in[0];
    const float* rw1    = (const float*)d_in[1];
    const float* action = (const float*)d_in[2];
    const float* noise  = (const float*)d_in[3];
    const int*   eidx   = (const int*)d_in[4];
    const float* W1     = (const float*)d_in[5];
    const float* b1     = (const float*)d_in[6];
    const float* Wg1    = (const float*)d_in[7];
    const float* bg1    = (const float*)d_in[8];
    const float* Whv    = (const float*)d_in[9];
    const float* bhv    = (const float*)d_in[10];
    const float* Wg2    = (const float*)d_in[11];
    const float* bg2    = (const float*)d_in[12];
    const int* src = eidx;
    const int* dst = eidx + NE;

    // Regions (u16 units), 12.8M each:
    // R0: edge staging (6.4MB, dies after sort)   R1: h -> hidden' (ld 128)
    // R2: unused spare                            R3: aggcat -> agghid (ld 128)
    ushort* R0 = (ushort*)d_ws;
    ushort* R1 = R0 + 12800000;
    ushort* R2 = R1 + 12800000;
    ushort* R3 = R2 + 12800000;
    unsigned* staging = (unsigned*)R0;
    float* dis  = (float*)(R3 + 12800000);
    int* rowptr = (int*)(dis + NN);              // NN+1
    ushort* esrc = (ushort*)(rowptr + NN + 4);   // u16 src ids
    ushort* Wt1  = esrc + NE;              // [128][256]
    ushort* Wtg1 = Wt1 + 128 * 256;        // [256][160]
    ushort* Whvt = Wtg1 + 256 * 160;       // [256][256]
    ushort* Wg2t = Whvt + 256 * 256;       // [128][128]
    float* wval  = (float*)(Wg2t + 128 * 128);   // [128]
    float2* aggra = (float2*)(wval + 128);       // [NN]
    float2* ra2   = aggra + NN;                  // [NN] prescaled (rw,act)
    int* bcur   = (int*)(ra2 + NN);              // [NBUCK]

    const int T = 256;
    const int gemmRows = (NN + 127) / 128;       // 391
    const int bucketBlocks = (NE + 2047) / 2048; // 391
    const int aggBlocks = (NN + 3) / 4;

    // ---- prep: weight transposes + bcur zero ----
    transpose_all<<<611, T, 0, stream>>>(W1, Wg1, Whv, Wg2, Wt1, Wtg1, Whvt, Wg2t,
                                         wval, bcur);

    // ---- COMBINED gemm1 (h plain bf16) + bucket_edges (independent) ----
    gemm1_bucket<<<gemmRows + bucketBlocks, 512, 0, stream>>>(
        x, Wt1, b1, R1, NN, gemmRows, src, dst, bcur, staging, NE);

    // ---- sort buckets -> rowptr/dis/ra2/esrc ----
    sort_bucket<<<NBUCK, 128, 0, stream>>>(staging, bcur, rowptr, dis, ra2,
                                           rw1, action, esrc, NN, NE);

    // ---- agg1 (per-edge norm) on h -> aggcat (R3) + rw/action -> aggra ----
    agg128<false, true><<<aggBlocks, T, 0, stream>>>(
        R1, R3, rowptr, esrc, dis, NN, ra2, aggra);

    // ---- FUSED gemm2+gemm3+reparam (r16 128-row version): hidden' -> R1 ----
    gemm23_fused<<<gemmRows, 512, 0, stream>>>(
        R3, NN, aggra, Wtg1, bg1, Whvt, bhv, R1, dis, noise);

    // ---- agg2 (prescaled) on hidden' -> agghid (R3) ----
    agg128<true, false><<<aggBlocks, T, 0, stream>>>(
        R1, R3, rowptr, esrc, dis, NN, nullptr, nullptr);

    // ---- gemm4 + fused value head: cols -> d_out f32, val -> d_out tail ----
    gemm_mfma<128, 128, true><<<gemmRows, 512, 0, stream>>>(
        R3, 128, NN, Wg2t, bg2, d_out, 128,
        wval, bg2, (float*)d_out + (size_t)NN * 128);
}